// Round 6
// baseline (134.717 us; speedup 1.0000x reference)
//
#include <hip/hip_runtime.h>
#include <hip/hip_bf16.h>
#include <math.h>

// Problem constants (B, N, D_IN, H, F) = (2, 2048, 512, 8, 64)
#define Bq   2
#define Nq   2048
#define DIN  512
#define Hq   8
#define Fq   64
#define NEG  0.2f

using short8 = __attribute__((ext_vector_type(8))) short;     // 8x16-bit (4 VGPRs)
using half8  = __attribute__((ext_vector_type(8))) _Float16;  // fp16 MFMA A/B
using half2v = __attribute__((ext_vector_type(2))) _Float16;  // v_pk_* operand
using f32x4  = __attribute__((ext_vector_type(4))) float;     // MFMA C/D

__device__ inline unsigned int bf16_rne(float x) {
    unsigned int u = __float_as_uint(x);
    u += 0x7fffu + ((u >> 16) & 1u);
    return u >> 16;
}
__device__ inline unsigned int f16u(float x) {
    union { _Float16 h; unsigned short u; } cv;
    cv.h = (_Float16)x;
    return (unsigned int)cv.u;
}

// float -> orderable unsigned key (monotone): max on key == max on float
__device__ inline unsigned int fkey(float x) {
    unsigned int b = __float_as_uint(x);
    return (b & 0x80000000u) ? ~b : (b | 0x80000000u);
}
__device__ inline float fkey_dec(unsigned int k) {
    unsigned int b = (k & 0x80000000u) ? (k ^ 0x80000000u) : ~k;
    return __uint_as_float(b);
}
#define NEG_INF_KEY 0x007FFFFFu   // fkey(-inf)

// ---------------------------------------------------------------------------
// Kernel 1 (prep): afrag (256 blocks) + wfrag (128 blocks), R8-validated.
// Block 0 additionally initializes the 16 per-bh emax atomic cells.
// ---------------------------------------------------------------------------
#define AFRAG_BLOCKS 256
#define WFRAG_BLOCKS 128

__global__ __launch_bounds__(256) void prep_kernel(
    const float* __restrict__ nodes, ushort* __restrict__ Afrag,
    const float* __restrict__ W,     ushort* __restrict__ Wfrag,
    unsigned int* __restrict__ emax_key)
{
    __shared__ __align__(16) char smem[16 * 516 * 4];   // 33 KB: max(As, Ws)
    const int bid = blockIdx.x;
    const int t   = threadIdx.x;

    if (bid == 0 && t < 16) emax_key[t] = NEG_INF_KEY;

    if (bid < AFRAG_BLOCKS) {
        float (*As)[516] = (float(*)[516])smem;
        const int mt = bid;
        {
            const int row = t >> 4, c = t & 15;
#pragma unroll
            for (int i = 0; i < 8; i++) {
                float4 v = *(const float4*)&nodes[((size_t)mt * 16 + row) * DIN + (c + i * 16) * 4];
                *(float4*)&As[row][(c + i * 16) * 4] = v;
            }
        }
        __syncthreads();
        const int lane = t & 63, ksg = t >> 6;
        const int quad = lane >> 4, l15 = lane & 15;
#pragma unroll
        for (int k2 = 0; k2 < 4; k2++) {
            int ks = ksg * 4 + k2;
            const float* src = &As[l15][ks * 32 + quad * 8];
            float4 f0 = *(const float4*)src;
            float4 f1 = *(const float4*)(src + 4);
            uint4 pk;
            pk.x = bf16_rne(f0.x) | (bf16_rne(f0.y) << 16);
            pk.y = bf16_rne(f0.z) | (bf16_rne(f0.w) << 16);
            pk.z = bf16_rne(f1.x) | (bf16_rne(f1.y) << 16);
            pk.w = bf16_rne(f1.z) | (bf16_rne(f1.w) << 16);
            *(uint4*)(Afrag + ((size_t)(mt * 16 + ks) * 64 + lane) * 8) = pk;
        }
        return;
    }

    {
        float (*Ws)[68] = (float(*)[68])smem;
        const int id = bid - AFRAG_BLOCKS;
        const int ks = id & 15, h = id >> 4;
        {
            const int row = t >> 3, c = t & 7;
            const float* src = &W[(size_t)(ks * 32 + row) * (Hq * Fq) + h * 64 + c * 8];
            float4 v0 = *(const float4*)src;
            float4 v1 = *(const float4*)(src + 4);
            *(float4*)&Ws[row][c * 8]     = v0;
            *(float4*)&Ws[row][c * 8 + 4] = v1;
        }
        __syncthreads();
        const int lane = t & 63, nf = t >> 6;
        const int quad = lane >> 4, l15 = lane & 15;
        float f[8];
#pragma unroll
        for (int jj = 0; jj < 8; jj++) f[jj] = Ws[quad * 8 + jj][nf * 16 + l15];
        uint4 pk;
        pk.x = bf16_rne(f[0]) | (bf16_rne(f[1]) << 16);
        pk.y = bf16_rne(f[2]) | (bf16_rne(f[3]) << 16);
        pk.z = bf16_rne(f[4]) | (bf16_rne(f[5]) << 16);
        pk.w = bf16_rne(f[6]) | (bf16_rne(f[7]) << 16);
        *(uint4*)(Wfrag + (((size_t)(h * 16 + ks) * 4 + nf) * 64 + lane) * 8) = pk;
    }
}

// ---------------------------------------------------------------------------
// Kernel 2 (work): gemm (blocks [0,512), R8-validated) + BYTE-mask pack
// (128 B/thread contiguous reads, R5-validated). Epilogue stores el_t and
// f16 tables Epk/Fpk, and feeds the per-bh er-max via key-encoded atomicMax
// (removes attn's 2048-element scan; er_t buffer deleted).
// ---------------------------------------------------------------------------
#define GEMM_BLOCKS 512
#define PACK_BLOCKS 1024   // B * 64 jw * 2048 i / 256 threads

__global__ __launch_bounds__(256) void work_kernel(
    const ushort* __restrict__ Afrag, const ushort* __restrict__ Wfrag,
    const float*  __restrict__ avec,
    ushort* __restrict__ Vfrag,      // [16 bh][64 s][4 nf][64 lane][8] fp16
    float* __restrict__ el_t,        // [16][2048]
    ushort* __restrict__ Epk,        // [16][2048] f16 exp(er)
    ushort* __restrict__ Fpk,        // [16][2048] f16 exp(NEG*er)
    unsigned int* __restrict__ emax_key,
    const int* __restrict__ edges, uint2* __restrict__ ebTB)
{
    const int bid = blockIdx.x;
    const int t   = threadIdx.x;

    if (bid >= GEMM_BLOCKS) {
        // ---- pack edges -> byte mask, 128 B/thread contiguous reads ----
        int gid = (bid - GEMM_BLOCKS) * 256 + t;   // 0..262143
        int i  = gid & 2047;
        int jw = (gid >> 11) & 63;
        int b  = gid >> 17;
        const int4* ep = (const int4*)(edges + (((size_t)b * Nq + i) * Nq + jw * 32));
        int4 v[8];
#pragma unroll
        for (int c = 0; c < 8; c++) v[c] = ep[c];
#pragma unroll
        for (int q = 0; q < 4; q++) {
            unsigned int lo = 0, hi = 0;
            lo |= v[2*q].x   ? 0x000000FFu : 0u;  lo |= v[2*q].y   ? 0x0000FF00u : 0u;
            lo |= v[2*q].z   ? 0x00FF0000u : 0u;  lo |= v[2*q].w   ? 0xFF000000u : 0u;
            hi |= v[2*q+1].x ? 0x000000FFu : 0u;  hi |= v[2*q+1].y ? 0x0000FF00u : 0u;
            hi |= v[2*q+1].z ? 0x00FF0000u : 0u;  hi |= v[2*q+1].w ? 0xFF000000u : 0u;
            uint2 w; w.x = lo; w.y = hi;
            ebTB[((size_t)(b * 256 + jw * 4 + q)) * 2048 + i] = w;
        }
        return;
    }

    // ---- gemm: R8-validated body ----
    const int lane = t & 63;
    const int wv   = t >> 6;
    const int quad = lane >> 4;
    const int l15  = lane & 15;
    const int h    = bid >> 6;            // 0..7
    const int mt   = (bid & 63) * 4 + wv; // 0..255
    const int row0 = mt * 16;

    const ushort* ap = Afrag + (size_t)mt * 8192 + lane * 8;   // + ks*512
    const ushort* bp = Wfrag + (size_t)h * 32768 + lane * 8;   // + ks*2048 + nf*512

    f32x4 zero4 = {0.f, 0.f, 0.f, 0.f};
    f32x4 acc[4] = {zero4, zero4, zero4, zero4};

    short8 a0, a1, b0[4], b1[4];
    a0 = *(const short8*)(ap);
#pragma unroll
    for (int nf = 0; nf < 4; nf++) b0[nf] = *(const short8*)(bp + nf * 512);

    for (int ks = 0; ks < 16; ks += 2) {
        a1 = *(const short8*)(ap + (ks + 1) * 512);
#pragma unroll
        for (int nf = 0; nf < 4; nf++) b1[nf] = *(const short8*)(bp + (ks + 1) * 2048 + nf * 512);
#pragma unroll
        for (int nf = 0; nf < 4; nf++)
            acc[nf] = __builtin_amdgcn_mfma_f32_16x16x32_bf16(a0, b0[nf], acc[nf], 0, 0, 0);
        a0 = *(const short8*)(ap + (ks + 2) * 512);   // ks=14 -> past end: lands in Wfrag, unused
#pragma unroll
        for (int nf = 0; nf < 4; nf++) b0[nf] = *(const short8*)(bp + (ks + 2) * 2048 + nf * 512);
#pragma unroll
        for (int nf = 0; nf < 4; nf++)
            acc[nf] = __builtin_amdgcn_mfma_f32_16x16x32_bf16(a1, b1[nf], acc[nf], 0, 0, 0);
    }

    // ---- fused el/er (+ f16 E/F tables, + er-max atomic) ----
    float aL[4], aR[4];
#pragma unroll
    for (int nf = 0; nf < 4; nf++) {
        aL[nf] = avec[nf * 16 + l15];
        aR[nf] = avec[Fq + nf * 16 + l15];
    }
    const int bb = row0 >> 11;
    const int bh = bb * Hq + h;
    float prmax = -INFINITY;
#pragma unroll
    for (int r = 0; r < 4; r++) {
        float pl = acc[0][r] * aL[0] + acc[1][r] * aL[1] + acc[2][r] * aL[2] + acc[3][r] * aL[3];
        float pr = acc[0][r] * aR[0] + acc[1][r] * aR[1] + acc[2][r] * aR[2] + acc[3][r] * aR[3];
#pragma unroll
        for (int off = 1; off < 16; off <<= 1) {
            pl += __shfl_xor(pl, off, 64);
            pr += __shfl_xor(pr, off, 64);
        }
        prmax = fmaxf(prmax, pr);
        if (l15 == 0) {
            int n = (row0 + quad * 4 + r) & (Nq - 1);
            el_t[(size_t)bh * Nq + n] = pl;
            Epk[(size_t)bh * Nq + n] = (ushort)f16u(__expf(pr));
            Fpk[(size_t)bh * Nq + n] = (ushort)f16u(__expf(NEG * pr));
        }
    }
    prmax = fmaxf(prmax, __shfl_xor(prmax, 16, 64));
    prmax = fmaxf(prmax, __shfl_xor(prmax, 32, 64));
    if (lane == 0) atomicMax(&emax_key[bh], fkey(prmax));

    // ---- Vfrag (fp16): C in attn B-fragment order (layout R3/R4/R7/R8) ----
    const int n_base = row0 & (Nq - 1);
    const int sblk   = n_base >> 5;
    const int quadp  = ((wv & 1) << 1) | (quad >> 1);
    const int jj0    = (quad & 1) * 4;
#pragma unroll
    for (int nf = 0; nf < 4; nf++) {
        uint2 pk;
        pk.x = f16u(acc[nf][0]) | (f16u(acc[nf][1]) << 16);
        pk.y = f16u(acc[nf][2]) | (f16u(acc[nf][3]) << 16);
        size_t off = ((((size_t)bh * 64 + sblk) * 4 + nf) * 64 + quadp * 16 + l15) * 8 + jj0;
        *(uint2*)(Vfrag + off) = pk;
    }
}

// ---------------------------------------------------------------------------
// Kernel 3: MFMA attention, fp16 (full-coverage R3 structure).
// P = max(A*E, C*F) (R4/R5-validated). Row sums l now via v_dot2_f32_f16 on
// the masked P pairs (f32 accumulate) instead of a 5th MFMA: MFMA pipe per
// s-iter drops 20/16 -> critical path shortens (attn was MFMA-bound).
// emax read from the precomputed atomic key (no scan, one less barrier).
// Output = attn/8 in fp16 (h-mean folded here).
// ---------------------------------------------------------------------------
__global__ __launch_bounds__(256, 2) void attn_kernel(
    const float* __restrict__ el_t,
    const unsigned int* __restrict__ emax_key,
    const ushort* __restrict__ Epk, const ushort* __restrict__ Fpk,
    const ushort* __restrict__ Vfrag,
    const uint2* __restrict__ ebTB, ushort* __restrict__ attn)
{
    const int lane = threadIdx.x & 63;
    const int kh   = threadIdx.x >> 6;     // j-quarter 0..3
    const int quad = lane >> 4;
    const int l15  = lane & 15;
    const int bid  = blockIdx.x;           // B*H*32 = 512
    const int it   = bid & 31;
    const int h    = (bid >> 5) & 7;
    const int b    = bid >> 8;             // 0..1 (full coverage)
    const int bh   = b * Hq + h;
    const int i0   = it * 64;

    __shared__ float lds_l[4][4][16];                        // [kh][rs][row16]
    __shared__ __align__(16) float lds_acc[4][4][4][64][4];  // [kh][rs][nf][lane][r] 64 KB

    const float emax = fkey_dec(emax_key[bh]);

    // ---- per-row broadcast (A,A) and (C,C) for 4 row-sets ----
    union HU { unsigned int u; half2v h; };
    HU AA2[4], CC2[4];
#pragma unroll
    for (int rs = 0; rs < 4; rs++) {
        float elv = el_t[(size_t)bh * Nq + i0 + rs * 16 + l15];
        float xm  = elv + emax;
        float m   = fmaxf(xm, NEG * xm);   // safe shift: s - m <= 0
        unsigned int a16 = f16u(__expf(elv - m));
        unsigned int c16 = f16u(__expf(NEG * elv - m));
        AA2[rs].u = a16 | (a16 << 16);
        CC2[rs].u = c16 | (c16 << 16);
    }

    const ushort* Ep = Epk + (size_t)bh * Nq + kh * 512;                    // + s*32
    const ushort* Fp = Fpk + (size_t)bh * Nq + kh * 512;                    // + s*32
    const ushort* vp = Vfrag + (size_t)bh * 131072 + kh * 32768 + lane * 8; // + s*2048
    const uint2*  mp = ebTB + ((size_t)(b * 256 + kh * 64 + quad)) * 2048 + i0 + l15;

    f32x4 zero4 = {0.f, 0.f, 0.f, 0.f};
    f32x4 acc[4][4];
    float lsum[4] = {0.f, 0.f, 0.f, 0.f};
#pragma unroll
    for (int rs = 0; rs < 4; rs++)
#pragma unroll
        for (int nf = 0; nf < 4; nf++) acc[rs][nf] = zero4;

    HU ones2;
    ones2.u = 0x3C003C00u;   // (1.0h, 1.0h)

    for (int s = 0; s < 16; s++) {
        half8 vb0 = *(const half8*)(vp + s * 2048);
        half8 vb1 = *(const half8*)(vp + s * 2048 + 512);
        half8 vb2 = *(const half8*)(vp + s * 2048 + 1024);
        half8 vb3 = *(const half8*)(vp + s * 2048 + 1536);
        uint2 mbs[4];
#pragma unroll
        for (int rs = 0; rs < 4; rs++) mbs[rs] = mp[(size_t)s * 8192 + rs * 16];
        uint4 ev = *(const uint4*)(Ep + s * 32 + quad * 8);   // 4x (E_2p, E_2p+1)
        uint4 fv = *(const uint4*)(Fp + s * 32 + quad * 8);
        unsigned int ee[4] = {ev.x, ev.y, ev.z, ev.w};
        unsigned int ff[4] = {fv.x, fv.y, fv.z, fv.w};

#pragma unroll
        for (int rs = 0; rs < 4; rs++) {
            union AFU { half8 h8; unsigned int w4[4]; } af;
#pragma unroll
            for (int pp = 0; pp < 4; pp++) {
                HU e, f, pe, pf, P;
                e.u = ee[pp];
                f.u = ff[pp];
                pe.h = AA2[rs].h * e.h;                    // (A*E_2p, A*E_2p+1)
                pf.h = CC2[rs].h * f.h;                    // (C*F_2p, C*F_2p+1)
                P.h = __builtin_elementwise_max(pe.h, pf.h);
                unsigned int msrc = (pp < 2) ? mbs[rs].x : mbs[rs].y;
                unsigned int msel = (pp & 1) ? 0x03030202u : 0x01010000u;
                af.w4[pp] = P.u & __builtin_amdgcn_perm(0u, msrc, msel);
            }
            // row-sum of masked P via dot2 (f32 accumulate)
#if __has_builtin(__builtin_amdgcn_fdot2)
#pragma unroll
            for (int pp = 0; pp < 4; pp++) {
                HU w; w.u = af.w4[pp];
                lsum[rs] = __builtin_amdgcn_fdot2(w.h, ones2.h, lsum[rs], false);
            }
#else
#pragma unroll
            for (int pp = 0; pp < 4; pp++) {
                HU w; w.u = af.w4[pp];
                lsum[rs] += (float)w.h[0] + (float)w.h[1];
            }
#endif
            acc[rs][0] = __builtin_amdgcn_mfma_f32_16x16x32_f16(af.h8, vb0, acc[rs][0], 0, 0, 0);
            acc[rs][1] = __builtin_amdgcn_mfma_f32_16x16x32_f16(af.h8, vb1, acc[rs][1], 0, 0, 0);
            acc[rs][2] = __builtin_amdgcn_mfma_f32_16x16x32_f16(af.h8, vb2, acc[rs][2], 0, 0, 0);
            acc[rs][3] = __builtin_amdgcn_mfma_f32_16x16x32_f16(af.h8, vb3, acc[rs][3], 0, 0, 0);
        }
    }

    // ---- l: cross-quad reduce; lane row = l15 ----
#pragma unroll
    for (int rs = 0; rs < 4; rs++) {
        lsum[rs] += __shfl_xor(lsum[rs], 16, 64);
        lsum[rs] += __shfl_xor(lsum[rs], 32, 64);
    }
    if (quad == 0) {
#pragma unroll
        for (int rs = 0; rs < 4; rs++) lds_l[kh][rs][l15] = lsum[rs];
    }

    // ---- cross-kh combine: store partials, reduce rs=kh ----
#pragma unroll
    for (int rs = 0; rs < 4; rs++)
#pragma unroll
        for (int nf = 0; nf < 4; nf++)
            *(f32x4*)&lds_acc[kh][rs][nf][lane][0] = acc[rs][nf];
    __syncthreads();

    const int rs = kh;
    f32x4 facc[4] = {zero4, zero4, zero4, zero4};
#pragma unroll
    for (int k2 = 0; k2 < 4; k2++)
#pragma unroll
        for (int nf = 0; nf < 4; nf++) {
            f32x4 v = *(const f32x4*)&lds_acc[k2][rs][nf][lane][0];
            facc[nf][0] += v[0]; facc[nf][1] += v[1];
            facc[nf][2] += v[2]; facc[nf][3] += v[3];
        }
    float rl[4];
#pragma unroll
    for (int r = 0; r < 4; r++) {
        float sl = 0.f;
#pragma unroll
        for (int k2 = 0; k2 < 4; k2++) sl += lds_l[k2][rs][quad * 4 + r];
        rl[r] = 1.0f / (8.0f * sl);            // h-mean folded in
    }
#pragma unroll
    for (int nf = 0; nf < 4; nf++)
#pragma unroll
        for (int r = 0; r < 4; r++)
            attn[(((size_t)b * Nq + i0 + rs * 16 + quad * 4 + r) * Hq + h) * Fq + nf * 16 + l15]
                = (ushort)f16u(facc[nf][r] * rl[r]);
}

// ---------------------------------------------------------------------------
// Kernel 4: out[b,i,f] = sigmoid( sum_h attn[b,i,h,f] )   (attn pre-scaled)
// Vectorized: 8 f per thread (ushort8 loads, float4 x2 store).
// ---------------------------------------------------------------------------
__global__ __launch_bounds__(256) void out_kernel(
    const ushort* __restrict__ attn, float* __restrict__ out)
{
    const int idx = blockIdx.x * 256 + threadIdx.x;   // 32768 threads
    const int f8  = idx & 7;
    const int bn  = idx >> 3;
    const ushort* p = attn + (size_t)bn * Hq * Fq + f8 * 8;
    float s[8] = {0.f, 0.f, 0.f, 0.f, 0.f, 0.f, 0.f, 0.f};
#pragma unroll
    for (int h = 0; h < Hq; h++) {
        union { short8 v; _Float16 h16[8]; } cv;
        cv.v = *(const short8*)(p + h * Fq);
#pragma unroll
        for (int j = 0; j < 8; j++) s[j] += (float)cv.h16[j];
    }
    float4 o0, o1;
    o0.x = 1.f / (1.f + __expf(-s[0]));  o0.y = 1.f / (1.f + __expf(-s[1]));
    o0.z = 1.f / (1.f + __expf(-s[2]));  o0.w = 1.f / (1.f + __expf(-s[3]));
    o1.x = 1.f / (1.f + __expf(-s[4]));  o1.y = 1.f / (1.f + __expf(-s[5]));
    o1.z = 1.f / (1.f + __expf(-s[6]));  o1.w = 1.f / (1.f + __expf(-s[7]));
    float* op = out + (size_t)bn * Fq + f8 * 8;
    *(float4*)op       = o0;
    *(float4*)(op + 4) = o1;
}

// ---------------------------------------------------------------------------
extern "C" void kernel_launch(void* const* d_in, const int* in_sizes, int n_in,
                              void* d_out, int out_size, void* d_ws, size_t ws_size,
                              hipStream_t stream) {
    const float* nodes = (const float*)d_in[0];   // (2,2048,512)
    const int*   edges = (const int*)d_in[1];     // (2,2048,2048,1)
    const float* W     = (const float*)d_in[2];   // (512,512)
    const float* a     = (const float*)d_in[3];   // (128,)
    float* out = (float*)d_out;                   // (2,2048,64)

    char* ws = (char*)d_ws;
    ushort* Afrag = (ushort*)ws;           ws += (size_t)Bq * Nq * DIN * 2;           // 4 MB
    ushort* Wfrag = (ushort*)ws;           ws += (size_t)DIN * Hq * Fq * 2;           // 512 KB
    ushort* Vfrag = (ushort*)ws;           ws += (size_t)Bq * Hq * Nq * Fq * 2;       // 4 MB
    float*  el_t  = (float*)ws;            ws += (size_t)Bq * Hq * Nq * 4;            // 128 KB
    ushort* Epk   = (ushort*)ws;           ws += (size_t)Bq * Hq * Nq * 2;            // 64 KB
    ushort* Fpk   = (ushort*)ws;           ws += (size_t)Bq * Hq * Nq * 2;            // 64 KB
    unsigned int* emax_key = (unsigned int*)ws; ws += 128;                            // 16 used
    uint2*  ebTB  = (uint2*)ws;            ws += (size_t)Bq * Nq * Nq;                // 8.4 MB
    ushort* attn  = (ushort*)ws;                                                      // 4 MB

    prep_kernel<<<AFRAG_BLOCKS + WFRAG_BLOCKS, 256, 0, stream>>>(nodes, Afrag, W, Wfrag, emax_key);
    work_kernel<<<GEMM_BLOCKS + PACK_BLOCKS, 256, 0, stream>>>(
        Afrag, Wfrag, a, Vfrag, el_t, Epk, Fpk, emax_key, edges, ebTB);
    attn_kernel<<<Bq * Hq * (Nq / 64), 256, 0, stream>>>(el_t, emax_key, Epk, Fpk, Vfrag, ebTB, attn);
    out_kernel<<<(Bq * Nq * Fq) / (256 * 8), 256, 0, stream>>>(attn, out);
}

// Round 7
// 132.800 us; speedup vs baseline: 1.0144x; 1.0144x over previous
//
#include <hip/hip_runtime.h>
#include <hip/hip_bf16.h>
#include <math.h>

// Problem constants (B, N, D_IN, H, F) = (2, 2048, 512, 8, 64)
#define Bq   2
#define Nq   2048
#define DIN  512
#define Hq   8
#define Fq   64
#define NEG  0.2f

using short8 = __attribute__((ext_vector_type(8))) short;     // 8x16-bit (4 VGPRs)
using half8  = __attribute__((ext_vector_type(8))) _Float16;  // fp16 MFMA A/B
using half2v = __attribute__((ext_vector_type(2))) _Float16;  // v_pk_* operand
using f32x4  = __attribute__((ext_vector_type(4))) float;     // MFMA C/D

__device__ inline unsigned int bf16_rne(float x) {
    unsigned int u = __float_as_uint(x);
    u += 0x7fffu + ((u >> 16) & 1u);
    return u >> 16;
}
__device__ inline unsigned int f16u(float x) {
    union { _Float16 h; unsigned short u; } cv;
    cv.h = (_Float16)x;
    return (unsigned int)cv.u;
}

// float -> orderable unsigned key (monotone): max on key == max on float
__device__ inline unsigned int fkey(float x) {
    unsigned int b = __float_as_uint(x);
    return (b & 0x80000000u) ? ~b : (b | 0x80000000u);
}
__device__ inline float fkey_dec(unsigned int k) {
    unsigned int b = (k & 0x80000000u) ? (k ^ 0x80000000u) : ~k;
    return __uint_as_float(b);
}
#define NEG_INF_KEY 0x007FFFFFu   // fkey(-inf)

// ---------------------------------------------------------------------------
// Kernel 1 (prep): afrag (256 blocks) + wfrag (128 blocks), R8-validated.
// Block 0 additionally initializes the 16 per-bh emax atomic cells.
// ---------------------------------------------------------------------------
#define AFRAG_BLOCKS 256
#define WFRAG_BLOCKS 128

__global__ __launch_bounds__(256) void prep_kernel(
    const float* __restrict__ nodes, ushort* __restrict__ Afrag,
    const float* __restrict__ W,     ushort* __restrict__ Wfrag,
    unsigned int* __restrict__ emax_key)
{
    __shared__ __align__(16) char smem[16 * 516 * 4];   // 33 KB: max(As, Ws)
    const int bid = blockIdx.x;
    const int t   = threadIdx.x;

    if (bid == 0 && t < 16) emax_key[t] = NEG_INF_KEY;

    if (bid < AFRAG_BLOCKS) {
        float (*As)[516] = (float(*)[516])smem;
        const int mt = bid;
        {
            const int row = t >> 4, c = t & 15;
#pragma unroll
            for (int i = 0; i < 8; i++) {
                float4 v = *(const float4*)&nodes[((size_t)mt * 16 + row) * DIN + (c + i * 16) * 4];
                *(float4*)&As[row][(c + i * 16) * 4] = v;
            }
        }
        __syncthreads();
        const int lane = t & 63, ksg = t >> 6;
        const int quad = lane >> 4, l15 = lane & 15;
#pragma unroll
        for (int k2 = 0; k2 < 4; k2++) {
            int ks = ksg * 4 + k2;
            const float* src = &As[l15][ks * 32 + quad * 8];
            float4 f0 = *(const float4*)src;
            float4 f1 = *(const float4*)(src + 4);
            uint4 pk;
            pk.x = bf16_rne(f0.x) | (bf16_rne(f0.y) << 16);
            pk.y = bf16_rne(f0.z) | (bf16_rne(f0.w) << 16);
            pk.z = bf16_rne(f1.x) | (bf16_rne(f1.y) << 16);
            pk.w = bf16_rne(f1.z) | (bf16_rne(f1.w) << 16);
            *(uint4*)(Afrag + ((size_t)(mt * 16 + ks) * 64 + lane) * 8) = pk;
        }
        return;
    }

    {
        float (*Ws)[68] = (float(*)[68])smem;
        const int id = bid - AFRAG_BLOCKS;
        const int ks = id & 15, h = id >> 4;
        {
            const int row = t >> 3, c = t & 7;
            const float* src = &W[(size_t)(ks * 32 + row) * (Hq * Fq) + h * 64 + c * 8];
            float4 v0 = *(const float4*)src;
            float4 v1 = *(const float4*)(src + 4);
            *(float4*)&Ws[row][c * 8]     = v0;
            *(float4*)&Ws[row][c * 8 + 4] = v1;
        }
        __syncthreads();
        const int lane = t & 63, nf = t >> 6;
        const int quad = lane >> 4, l15 = lane & 15;
        float f[8];
#pragma unroll
        for (int jj = 0; jj < 8; jj++) f[jj] = Ws[quad * 8 + jj][nf * 16 + l15];
        uint4 pk;
        pk.x = bf16_rne(f[0]) | (bf16_rne(f[1]) << 16);
        pk.y = bf16_rne(f[2]) | (bf16_rne(f[3]) << 16);
        pk.z = bf16_rne(f[4]) | (bf16_rne(f[5]) << 16);
        pk.w = bf16_rne(f[6]) | (bf16_rne(f[7]) << 16);
        *(uint4*)(Wfrag + (((size_t)(h * 16 + ks) * 4 + nf) * 64 + lane) * 8) = pk;
    }
}

// ---------------------------------------------------------------------------
// Kernel 2 (work): gemm (blocks [0,512), R8-validated) + BYTE-mask pack
// (128 B/thread contiguous reads, R5-validated). Epilogue stores el_t and
// f16 tables Epk/Fpk, and feeds per-bh er-max via key-encoded atomicMax
// (replaces attn's 2048-element scan; er_t buffer deleted).
// ---------------------------------------------------------------------------
#define GEMM_BLOCKS 512
#define PACK_BLOCKS 1024   // B * 64 jw * 2048 i / 256 threads

__global__ __launch_bounds__(256) void work_kernel(
    const ushort* __restrict__ Afrag, const ushort* __restrict__ Wfrag,
    const float*  __restrict__ avec,
    ushort* __restrict__ Vfrag,      // [16 bh][64 s][4 nf][64 lane][8] fp16
    float* __restrict__ el_t,        // [16][2048]
    ushort* __restrict__ Epk,        // [16][2048] f16 exp(er)
    ushort* __restrict__ Fpk,        // [16][2048] f16 exp(NEG*er)
    unsigned int* __restrict__ emax_key,
    const int* __restrict__ edges, uint2* __restrict__ ebTB)
{
    const int bid = blockIdx.x;
    const int t   = threadIdx.x;

    if (bid >= GEMM_BLOCKS) {
        // ---- pack edges -> byte mask, 128 B/thread contiguous reads ----
        int gid = (bid - GEMM_BLOCKS) * 256 + t;   // 0..262143
        int i  = gid & 2047;
        int jw = (gid >> 11) & 63;
        int b  = gid >> 17;
        const int4* ep = (const int4*)(edges + (((size_t)b * Nq + i) * Nq + jw * 32));
        int4 v[8];
#pragma unroll
        for (int c = 0; c < 8; c++) v[c] = ep[c];
#pragma unroll
        for (int q = 0; q < 4; q++) {
            unsigned int lo = 0, hi = 0;
            lo |= v[2*q].x   ? 0x000000FFu : 0u;  lo |= v[2*q].y   ? 0x0000FF00u : 0u;
            lo |= v[2*q].z   ? 0x00FF0000u : 0u;  lo |= v[2*q].w   ? 0xFF000000u : 0u;
            hi |= v[2*q+1].x ? 0x000000FFu : 0u;  hi |= v[2*q+1].y ? 0x0000FF00u : 0u;
            hi |= v[2*q+1].z ? 0x00FF0000u : 0u;  hi |= v[2*q+1].w ? 0xFF000000u : 0u;
            uint2 w; w.x = lo; w.y = hi;
            ebTB[((size_t)(b * 256 + jw * 4 + q)) * 2048 + i] = w;
        }
        return;
    }

    // ---- gemm: R8-validated body ----
    const int lane = t & 63;
    const int wv   = t >> 6;
    const int quad = lane >> 4;
    const int l15  = lane & 15;
    const int h    = bid >> 6;            // 0..7
    const int mt   = (bid & 63) * 4 + wv; // 0..255
    const int row0 = mt * 16;

    const ushort* ap = Afrag + (size_t)mt * 8192 + lane * 8;   // + ks*512
    const ushort* bp = Wfrag + (size_t)h * 32768 + lane * 8;   // + ks*2048 + nf*512

    f32x4 zero4 = {0.f, 0.f, 0.f, 0.f};
    f32x4 acc[4] = {zero4, zero4, zero4, zero4};

    short8 a0, a1, b0[4], b1[4];
    a0 = *(const short8*)(ap);
#pragma unroll
    for (int nf = 0; nf < 4; nf++) b0[nf] = *(const short8*)(bp + nf * 512);

    for (int ks = 0; ks < 16; ks += 2) {
        a1 = *(const short8*)(ap + (ks + 1) * 512);
#pragma unroll
        for (int nf = 0; nf < 4; nf++) b1[nf] = *(const short8*)(bp + (ks + 1) * 2048 + nf * 512);
#pragma unroll
        for (int nf = 0; nf < 4; nf++)
            acc[nf] = __builtin_amdgcn_mfma_f32_16x16x32_bf16(a0, b0[nf], acc[nf], 0, 0, 0);
        a0 = *(const short8*)(ap + (ks + 2) * 512);   // ks=14 -> past end: lands in Wfrag, unused
#pragma unroll
        for (int nf = 0; nf < 4; nf++) b0[nf] = *(const short8*)(bp + (ks + 2) * 2048 + nf * 512);
#pragma unroll
        for (int nf = 0; nf < 4; nf++)
            acc[nf] = __builtin_amdgcn_mfma_f32_16x16x32_bf16(a1, b1[nf], acc[nf], 0, 0, 0);
    }

    // ---- fused el/er (+ f16 E/F tables, + er-max atomic) ----
    float aL[4], aR[4];
#pragma unroll
    for (int nf = 0; nf < 4; nf++) {
        aL[nf] = avec[nf * 16 + l15];
        aR[nf] = avec[Fq + nf * 16 + l15];
    }
    const int bb = row0 >> 11;
    const int bh = bb * Hq + h;
    float prmax = -INFINITY;
#pragma unroll
    for (int r = 0; r < 4; r++) {
        float pl = acc[0][r] * aL[0] + acc[1][r] * aL[1] + acc[2][r] * aL[2] + acc[3][r] * aL[3];
        float pr = acc[0][r] * aR[0] + acc[1][r] * aR[1] + acc[2][r] * aR[2] + acc[3][r] * aR[3];
#pragma unroll
        for (int off = 1; off < 16; off <<= 1) {
            pl += __shfl_xor(pl, off, 64);
            pr += __shfl_xor(pr, off, 64);
        }
        prmax = fmaxf(prmax, pr);
        if (l15 == 0) {
            int n = (row0 + quad * 4 + r) & (Nq - 1);
            el_t[(size_t)bh * Nq + n] = pl;
            Epk[(size_t)bh * Nq + n] = (ushort)f16u(__expf(pr));
            Fpk[(size_t)bh * Nq + n] = (ushort)f16u(__expf(NEG * pr));
        }
    }
    prmax = fmaxf(prmax, __shfl_xor(prmax, 16, 64));
    prmax = fmaxf(prmax, __shfl_xor(prmax, 32, 64));
    if (lane == 0) atomicMax(&emax_key[bh], fkey(prmax));

    // ---- Vfrag (fp16): C in attn B-fragment order (layout R3/R4/R7/R8) ----
    const int n_base = row0 & (Nq - 1);
    const int sblk   = n_base >> 5;
    const int quadp  = ((wv & 1) << 1) | (quad >> 1);
    const int jj0    = (quad & 1) * 4;
#pragma unroll
    for (int nf = 0; nf < 4; nf++) {
        uint2 pk;
        pk.x = f16u(acc[nf][0]) | (f16u(acc[nf][1]) << 16);
        pk.y = f16u(acc[nf][2]) | (f16u(acc[nf][3]) << 16);
        size_t off = ((((size_t)bh * 64 + sblk) * 4 + nf) * 64 + quadp * 16 + l15) * 8 + jj0;
        *(uint2*)(Vfrag + off) = pk;
    }
}

// ---------------------------------------------------------------------------
// Kernel 3: MFMA attention, fp16 (R5-validated inner loop, byte-identical).
// P = max(A*E, C*F); 5 ops/pair; row sums via 5th MFMA (B=ones).
// ONLY change vs R5: emax comes from the precomputed atomic key (uniform
// load) instead of a 2048-element er_t scan + barrier.
// ---------------------------------------------------------------------------
__global__ __launch_bounds__(256, 2) void attn_kernel(
    const float* __restrict__ el_t,
    const unsigned int* __restrict__ emax_key,
    const ushort* __restrict__ Epk, const ushort* __restrict__ Fpk,
    const ushort* __restrict__ Vfrag,
    const uint2* __restrict__ ebTB, ushort* __restrict__ attn)
{
    const int lane = threadIdx.x & 63;
    const int kh   = threadIdx.x >> 6;     // j-quarter 0..3
    const int quad = lane >> 4;
    const int l15  = lane & 15;
    const int bid  = blockIdx.x;           // B*H*32 = 512
    const int it   = bid & 31;
    const int h    = (bid >> 5) & 7;
    const int b    = bid >> 8;             // 0..1 (full coverage)
    const int bh   = b * Hq + h;
    const int i0   = it * 64;

    __shared__ float lds_l[4][4][16];                        // [kh][rs][row16]
    __shared__ __align__(16) float lds_acc[4][4][4][64][4];  // [kh][rs][nf][lane][r] 64 KB

    const float emax = fkey_dec(emax_key[bh]);

    // ---- per-row broadcast (A,A) and (C,C) for 4 row-sets ----
    union HU { unsigned int u; half2v h; };
    HU AA2[4], CC2[4];
#pragma unroll
    for (int rs = 0; rs < 4; rs++) {
        float elv = el_t[(size_t)bh * Nq + i0 + rs * 16 + l15];
        float xm  = elv + emax;
        float m   = fmaxf(xm, NEG * xm);   // safe shift: s - m <= 0
        unsigned int a16 = f16u(__expf(elv - m));
        unsigned int c16 = f16u(__expf(NEG * elv - m));
        AA2[rs].u = a16 | (a16 << 16);
        CC2[rs].u = c16 | (c16 << 16);
    }

    const ushort* Ep = Epk + (size_t)bh * Nq + kh * 512;                    // + s*32
    const ushort* Fp = Fpk + (size_t)bh * Nq + kh * 512;                    // + s*32
    const ushort* vp = Vfrag + (size_t)bh * 131072 + kh * 32768 + lane * 8; // + s*2048
    const uint2*  mp = ebTB + ((size_t)(b * 256 + kh * 64 + quad)) * 2048 + i0 + l15;

    f32x4 zero4 = {0.f, 0.f, 0.f, 0.f};
    f32x4 acc[4][4];
    f32x4 accl[4];
#pragma unroll
    for (int rs = 0; rs < 4; rs++) {
        accl[rs] = zero4;
#pragma unroll
        for (int nf = 0; nf < 4; nf++) acc[rs][nf] = zero4;
    }

    const _Float16 one16 = (_Float16)1.0f;
    const half8 onesv = {one16, one16, one16, one16, one16, one16, one16, one16};

    for (int s = 0; s < 16; s++) {
        half8 vb0 = *(const half8*)(vp + s * 2048);
        half8 vb1 = *(const half8*)(vp + s * 2048 + 512);
        half8 vb2 = *(const half8*)(vp + s * 2048 + 1024);
        half8 vb3 = *(const half8*)(vp + s * 2048 + 1536);
        uint2 mbs[4];
#pragma unroll
        for (int rs = 0; rs < 4; rs++) mbs[rs] = mp[(size_t)s * 8192 + rs * 16];
        uint4 ev = *(const uint4*)(Ep + s * 32 + quad * 8);   // 4x (E_2p, E_2p+1)
        uint4 fv = *(const uint4*)(Fp + s * 32 + quad * 8);
        unsigned int ee[4] = {ev.x, ev.y, ev.z, ev.w};
        unsigned int ff[4] = {fv.x, fv.y, fv.z, fv.w};

#pragma unroll
        for (int rs = 0; rs < 4; rs++) {
            union AFU { half8 h8; unsigned int w4[4]; } af;
#pragma unroll
            for (int pp = 0; pp < 4; pp++) {
                HU e, f, pe, pf, P;
                e.u = ee[pp];
                f.u = ff[pp];
                pe.h = AA2[rs].h * e.h;                    // (A*E_2p, A*E_2p+1)
                pf.h = CC2[rs].h * f.h;                    // (C*F_2p, C*F_2p+1)
                P.h = __builtin_elementwise_max(pe.h, pf.h);
                unsigned int msrc = (pp < 2) ? mbs[rs].x : mbs[rs].y;
                unsigned int msel = (pp & 1) ? 0x03030202u : 0x01010000u;
                af.w4[pp] = P.u & __builtin_amdgcn_perm(0u, msrc, msel);
            }
            acc[rs][0] = __builtin_amdgcn_mfma_f32_16x16x32_f16(af.h8, vb0, acc[rs][0], 0, 0, 0);
            acc[rs][1] = __builtin_amdgcn_mfma_f32_16x16x32_f16(af.h8, vb1, acc[rs][1], 0, 0, 0);
            acc[rs][2] = __builtin_amdgcn_mfma_f32_16x16x32_f16(af.h8, vb2, acc[rs][2], 0, 0, 0);
            acc[rs][3] = __builtin_amdgcn_mfma_f32_16x16x32_f16(af.h8, vb3, acc[rs][3], 0, 0, 0);
            accl[rs]   = __builtin_amdgcn_mfma_f32_16x16x32_f16(af.h8, onesv, accl[rs], 0, 0, 0);
        }
    }

    // ---- cross-kh combine: store partials (acc + l), reduce rs=kh ----
#pragma unroll
    for (int rs = 0; rs < 4; rs++)
#pragma unroll
        for (int nf = 0; nf < 4; nf++)
            *(f32x4*)&lds_acc[kh][rs][nf][lane][0] = acc[rs][nf];
    if (l15 == 0) {
#pragma unroll
        for (int rs = 0; rs < 4; rs++)
#pragma unroll
            for (int r = 0; r < 4; r++)
                lds_l[kh][rs][quad * 4 + r] = accl[rs][r];
    }
    __syncthreads();

    const int rs = kh;
    f32x4 facc[4] = {zero4, zero4, zero4, zero4};
#pragma unroll
    for (int k2 = 0; k2 < 4; k2++)
#pragma unroll
        for (int nf = 0; nf < 4; nf++) {
            f32x4 v = *(const f32x4*)&lds_acc[k2][rs][nf][lane][0];
            facc[nf][0] += v[0]; facc[nf][1] += v[1];
            facc[nf][2] += v[2]; facc[nf][3] += v[3];
        }
    float rl[4];
#pragma unroll
    for (int r = 0; r < 4; r++) {
        float sl = 0.f;
#pragma unroll
        for (int k2 = 0; k2 < 4; k2++) sl += lds_l[k2][rs][quad * 4 + r];
        rl[r] = 1.0f / sl;
    }
#pragma unroll
    for (int nf = 0; nf < 4; nf++)
#pragma unroll
        for (int r = 0; r < 4; r++)
            attn[(((size_t)b * Nq + i0 + rs * 16 + quad * 4 + r) * Hq + h) * Fq + nf * 16 + l15]
                = (ushort)f16u(facc[nf][r] * rl[r]);
}

// ---------------------------------------------------------------------------
// Kernel 4: out[b,i,f] = sigmoid( mean_h attn[b,i,h,f] ), attn in fp16
// (R5-validated form, byte-identical.)
// ---------------------------------------------------------------------------
__global__ __launch_bounds__(256) void out_kernel(
    const ushort* __restrict__ attn, float* __restrict__ out)
{
    const int idx = blockIdx.x * 256 + threadIdx.x;
    const int f   = idx & 63;
    const int bn  = idx >> 6;
    const ushort* p = attn + (size_t)bn * Hq * Fq + f;
    float s = 0.f;
#pragma unroll
    for (int h = 0; h < Hq; h++) {
        union { ushort u; _Float16 h16; } cv;
        cv.u = p[h * Fq];
        s += (float)cv.h16;
    }
    s *= (1.f / Hq);
    out[idx] = 1.f / (1.f + __expf(-s));
}

// ---------------------------------------------------------------------------
extern "C" void kernel_launch(void* const* d_in, const int* in_sizes, int n_in,
                              void* d_out, int out_size, void* d_ws, size_t ws_size,
                              hipStream_t stream) {
    const float* nodes = (const float*)d_in[0];   // (2,2048,512)
    const int*   edges = (const int*)d_in[1];     // (2,2048,2048,1)
    const float* W     = (const float*)d_in[2];   // (512,512)
    const float* a     = (const float*)d_in[3];   // (128,)
    float* out = (float*)d_out;                   // (2,2048,64)

    char* ws = (char*)d_ws;
    ushort* Afrag = (ushort*)ws;           ws += (size_t)Bq * Nq * DIN * 2;           // 4 MB
    ushort* Wfrag = (ushort*)ws;           ws += (size_t)DIN * Hq * Fq * 2;           // 512 KB
    ushort* Vfrag = (ushort*)ws;           ws += (size_t)Bq * Hq * Nq * Fq * 2;       // 4 MB
    float*  el_t  = (float*)ws;            ws += (size_t)Bq * Hq * Nq * 4;            // 128 KB
    ushort* Epk   = (ushort*)ws;           ws += (size_t)Bq * Hq * Nq * 2;            // 64 KB
    ushort* Fpk   = (ushort*)ws;           ws += (size_t)Bq * Hq * Nq * 2;            // 64 KB
    unsigned int* emax_key = (unsigned int*)ws; ws += 128;                            // 16 used
    uint2*  ebTB  = (uint2*)ws;            ws += (size_t)Bq * Nq * Nq;                // 8.4 MB
    ushort* attn  = (ushort*)ws;                                                      // 4 MB

    prep_kernel<<<AFRAG_BLOCKS + WFRAG_BLOCKS, 256, 0, stream>>>(nodes, Afrag, W, Wfrag, emax_key);
    work_kernel<<<GEMM_BLOCKS + PACK_BLOCKS, 256, 0, stream>>>(
        Afrag, Wfrag, a, Vfrag, el_t, Epk, Fpk, emax_key, edges, ebTB);
    attn_kernel<<<Bq * Hq * (Nq / 64), 256, 0, stream>>>(el_t, emax_key, Epk, Fpk, Vfrag, ebTB, attn);
    out_kernel<<<(Bq * Nq * Fq) / 256, 256, 0, stream>>>(attn, out);
}

// Round 8
// 112.097 us; speedup vs baseline: 1.2018x; 1.1847x over previous
//
#include <hip/hip_runtime.h>
#include <hip/hip_bf16.h>
#include <math.h>

// Problem constants (B, N, D_IN, H, F) = (2, 2048, 512, 8, 64)
#define Bq   2
#define Nq   2048
#define DIN  512
#define Hq   8
#define Fq   64
#define NEG  0.2f

using short8 = __attribute__((ext_vector_type(8))) short;     // 8x16-bit (4 VGPRs)
using half8  = __attribute__((ext_vector_type(8))) _Float16;  // fp16 MFMA A/B
using half2v = __attribute__((ext_vector_type(2))) _Float16;  // v_pk_* operand
using f32x4  = __attribute__((ext_vector_type(4))) float;     // MFMA C/D

__device__ inline unsigned int bf16_rne(float x) {
    unsigned int u = __float_as_uint(x);
    u += 0x7fffu + ((u >> 16) & 1u);
    return u >> 16;
}
__device__ inline unsigned int f16u(float x) {
    union { _Float16 h; unsigned short u; } cv;
    cv.h = (_Float16)x;
    return (unsigned int)cv.u;
}

// ---------------------------------------------------------------------------
// Kernel 1 (prep): afrag (256 blocks) + wfrag (128 blocks), R8-validated.
// ---------------------------------------------------------------------------
#define AFRAG_BLOCKS 256
#define WFRAG_BLOCKS 128

__global__ __launch_bounds__(256) void prep_kernel(
    const float* __restrict__ nodes, ushort* __restrict__ Afrag,
    const float* __restrict__ W,     ushort* __restrict__ Wfrag)
{
    __shared__ __align__(16) char smem[16 * 516 * 4];   // 33 KB: max(As, Ws)
    const int bid = blockIdx.x;
    const int t   = threadIdx.x;

    if (bid < AFRAG_BLOCKS) {
        float (*As)[516] = (float(*)[516])smem;
        const int mt = bid;
        {
            const int row = t >> 4, c = t & 15;
#pragma unroll
            for (int i = 0; i < 8; i++) {
                float4 v = *(const float4*)&nodes[((size_t)mt * 16 + row) * DIN + (c + i * 16) * 4];
                *(float4*)&As[row][(c + i * 16) * 4] = v;
            }
        }
        __syncthreads();
        const int lane = t & 63, ksg = t >> 6;
        const int quad = lane >> 4, l15 = lane & 15;
#pragma unroll
        for (int k2 = 0; k2 < 4; k2++) {
            int ks = ksg * 4 + k2;
            const float* src = &As[l15][ks * 32 + quad * 8];
            float4 f0 = *(const float4*)src;
            float4 f1 = *(const float4*)(src + 4);
            uint4 pk;
            pk.x = bf16_rne(f0.x) | (bf16_rne(f0.y) << 16);
            pk.y = bf16_rne(f0.z) | (bf16_rne(f0.w) << 16);
            pk.z = bf16_rne(f1.x) | (bf16_rne(f1.y) << 16);
            pk.w = bf16_rne(f1.z) | (bf16_rne(f1.w) << 16);
            *(uint4*)(Afrag + ((size_t)(mt * 16 + ks) * 64 + lane) * 8) = pk;
        }
        return;
    }

    {
        float (*Ws)[68] = (float(*)[68])smem;
        const int id = bid - AFRAG_BLOCKS;
        const int ks = id & 15, h = id >> 4;
        {
            const int row = t >> 3, c = t & 7;
            const float* src = &W[(size_t)(ks * 32 + row) * (Hq * Fq) + h * 64 + c * 8];
            float4 v0 = *(const float4*)src;
            float4 v1 = *(const float4*)(src + 4);
            *(float4*)&Ws[row][c * 8]     = v0;
            *(float4*)&Ws[row][c * 8 + 4] = v1;
        }
        __syncthreads();
        const int lane = t & 63, nf = t >> 6;
        const int quad = lane >> 4, l15 = lane & 15;
        float f[8];
#pragma unroll
        for (int jj = 0; jj < 8; jj++) f[jj] = Ws[quad * 8 + jj][nf * 16 + l15];
        uint4 pk;
        pk.x = bf16_rne(f[0]) | (bf16_rne(f[1]) << 16);
        pk.y = bf16_rne(f[2]) | (bf16_rne(f[3]) << 16);
        pk.z = bf16_rne(f[4]) | (bf16_rne(f[5]) << 16);
        pk.w = bf16_rne(f[6]) | (bf16_rne(f[7]) << 16);
        *(uint4*)(Wfrag + (((size_t)(h * 16 + ks) * 4 + nf) * 64 + lane) * 8) = pk;
    }
}

// ---------------------------------------------------------------------------
// Kernel 2 (work): gemm (blocks [0,512), R8-validated) + BYTE-mask pack.
// Pack: 128 B/thread contiguous reads (8x int4: two full 64-B lines, zero
// over-fetch), emitting 4x uint2 byte-mask words per thread (i-coalesced).
// Epilogue stores el_t, er_t (f32) and packed f16 tables Epk/Fpk.
// NOTE (R7 lesson): do NOT compute er-max via a grid-wide atomicMax into a
// single cache line — same-line device-scope atomics serialize and cost
// ~+19 us. The per-block er_t scan in attn is the cheaper design.
// ---------------------------------------------------------------------------
#define GEMM_BLOCKS 512
#define PACK_BLOCKS 1024   // B * 64 jw * 2048 i / 256 threads

__global__ __launch_bounds__(256) void work_kernel(
    const ushort* __restrict__ Afrag, const ushort* __restrict__ Wfrag,
    const float*  __restrict__ avec,
    ushort* __restrict__ Vfrag,      // [16 bh][64 s][4 nf][64 lane][8] fp16
    float* __restrict__ el_t,        // [16][2048]
    float* __restrict__ er_t,        // [16][2048]
    ushort* __restrict__ Epk,        // [16][2048] f16 exp(er)
    ushort* __restrict__ Fpk,        // [16][2048] f16 exp(NEG*er)
    const int* __restrict__ edges, uint2* __restrict__ ebTB)
{
    const int bid = blockIdx.x;
    const int t   = threadIdx.x;

    if (bid >= GEMM_BLOCKS) {
        // ---- pack edges -> byte mask, 128 B/thread contiguous reads ----
        int gid = (bid - GEMM_BLOCKS) * 256 + t;   // 0..262143
        int i  = gid & 2047;
        int jw = (gid >> 11) & 63;
        int b  = gid >> 17;
        const int4* ep = (const int4*)(edges + (((size_t)b * Nq + i) * Nq + jw * 32));
        int4 v[8];
#pragma unroll
        for (int c = 0; c < 8; c++) v[c] = ep[c];
#pragma unroll
        for (int q = 0; q < 4; q++) {
            unsigned int lo = 0, hi = 0;
            lo |= v[2*q].x   ? 0x000000FFu : 0u;  lo |= v[2*q].y   ? 0x0000FF00u : 0u;
            lo |= v[2*q].z   ? 0x00FF0000u : 0u;  lo |= v[2*q].w   ? 0xFF000000u : 0u;
            hi |= v[2*q+1].x ? 0x000000FFu : 0u;  hi |= v[2*q+1].y ? 0x0000FF00u : 0u;
            hi |= v[2*q+1].z ? 0x00FF0000u : 0u;  hi |= v[2*q+1].w ? 0xFF000000u : 0u;
            uint2 w; w.x = lo; w.y = hi;
            ebTB[((size_t)(b * 256 + jw * 4 + q)) * 2048 + i] = w;
        }
        return;
    }

    // ---- gemm: R8-validated body ----
    const int lane = t & 63;
    const int wv   = t >> 6;
    const int quad = lane >> 4;
    const int l15  = lane & 15;
    const int h    = bid >> 6;            // 0..7
    const int mt   = (bid & 63) * 4 + wv; // 0..255
    const int row0 = mt * 16;

    const ushort* ap = Afrag + (size_t)mt * 8192 + lane * 8;   // + ks*512
    const ushort* bp = Wfrag + (size_t)h * 32768 + lane * 8;   // + ks*2048 + nf*512

    f32x4 zero4 = {0.f, 0.f, 0.f, 0.f};
    f32x4 acc[4] = {zero4, zero4, zero4, zero4};

    short8 a0, a1, b0[4], b1[4];
    a0 = *(const short8*)(ap);
#pragma unroll
    for (int nf = 0; nf < 4; nf++) b0[nf] = *(const short8*)(bp + nf * 512);

    for (int ks = 0; ks < 16; ks += 2) {
        a1 = *(const short8*)(ap + (ks + 1) * 512);
#pragma unroll
        for (int nf = 0; nf < 4; nf++) b1[nf] = *(const short8*)(bp + (ks + 1) * 2048 + nf * 512);
#pragma unroll
        for (int nf = 0; nf < 4; nf++)
            acc[nf] = __builtin_amdgcn_mfma_f32_16x16x32_bf16(a0, b0[nf], acc[nf], 0, 0, 0);
        a0 = *(const short8*)(ap + (ks + 2) * 512);   // ks=14 -> past end: lands in Wfrag, unused
#pragma unroll
        for (int nf = 0; nf < 4; nf++) b0[nf] = *(const short8*)(bp + (ks + 2) * 2048 + nf * 512);
#pragma unroll
        for (int nf = 0; nf < 4; nf++)
            acc[nf] = __builtin_amdgcn_mfma_f32_16x16x32_bf16(a1, b1[nf], acc[nf], 0, 0, 0);
    }

    // ---- fused el/er (+ packed-pair E/F tables) ----
    float aL[4], aR[4];
#pragma unroll
    for (int nf = 0; nf < 4; nf++) {
        aL[nf] = avec[nf * 16 + l15];
        aR[nf] = avec[Fq + nf * 16 + l15];
    }
    const int bb = row0 >> 11;
    const int bh = bb * Hq + h;
#pragma unroll
    for (int r = 0; r < 4; r++) {
        float pl = acc[0][r] * aL[0] + acc[1][r] * aL[1] + acc[2][r] * aL[2] + acc[3][r] * aL[3];
        float pr = acc[0][r] * aR[0] + acc[1][r] * aR[1] + acc[2][r] * aR[2] + acc[3][r] * aR[3];
#pragma unroll
        for (int off = 1; off < 16; off <<= 1) {
            pl += __shfl_xor(pl, off, 64);
            pr += __shfl_xor(pr, off, 64);
        }
        if (l15 == 0) {
            int n = (row0 + quad * 4 + r) & (Nq - 1);
            el_t[(size_t)bh * Nq + n] = pl;
            er_t[(size_t)bh * Nq + n] = pr;
            Epk[(size_t)bh * Nq + n] = (ushort)f16u(__expf(pr));
            Fpk[(size_t)bh * Nq + n] = (ushort)f16u(__expf(NEG * pr));
        }
    }

    // ---- Vfrag (fp16): C in attn B-fragment order (layout R3/R4/R7/R8) ----
    const int n_base = row0 & (Nq - 1);
    const int sblk   = n_base >> 5;
    const int quadp  = ((wv & 1) << 1) | (quad >> 1);
    const int jj0    = (quad & 1) * 4;
#pragma unroll
    for (int nf = 0; nf < 4; nf++) {
        uint2 pk;
        pk.x = f16u(acc[nf][0]) | (f16u(acc[nf][1]) << 16);
        pk.y = f16u(acc[nf][2]) | (f16u(acc[nf][3]) << 16);
        size_t off = ((((size_t)bh * 64 + sblk) * 4 + nf) * 64 + quadp * 16 + l15) * 8 + jj0;
        *(uint2*)(Vfrag + off) = pk;
    }
}

// ---------------------------------------------------------------------------
// Kernel 3: MFMA attention, fp16 pipeline (full-coverage structure from R3).
// P = exp(leaky(el+er) - m) = max(A*E, C*F); A,C broadcast as (A,A),(C,C);
// E,F loaded as packed CONSECUTIVE pairs -> per j-pair:
//   2 v_pk_mul_f16 + 1 v_pk_max_f16 + perm/and mask  (5 ops).
// Row sums via 5th MFMA (B=ones). Output stored fp16.
// emax via per-block er_t scan (R5-validated; cheaper than grid atomics).
// ---------------------------------------------------------------------------
__global__ __launch_bounds__(256, 2) void attn_kernel(
    const float* __restrict__ el_t, const float* __restrict__ er_t,
    const ushort* __restrict__ Epk, const ushort* __restrict__ Fpk,
    const ushort* __restrict__ Vfrag,
    const uint2* __restrict__ ebTB, ushort* __restrict__ attn)
{
    const int lane = threadIdx.x & 63;
    const int kh   = threadIdx.x >> 6;     // j-quarter 0..3
    const int quad = lane >> 4;
    const int l15  = lane & 15;
    const int bid  = blockIdx.x;           // B*H*32 = 512
    const int it   = bid & 31;
    const int h    = (bid >> 5) & 7;
    const int b    = bid >> 8;             // 0..1 (full coverage)
    const int bh   = b * Hq + h;
    const int i0   = it * 64;

    __shared__ float smax[4];
    __shared__ float lds_l[4][4][16];                        // [kh][rs][row16]
    __shared__ __align__(16) float lds_acc[4][4][4][64][4];  // [kh][rs][nf][lane][r] 64 KB

    // ---- ermax over er_t[bh][:] ----
    const float* errow = er_t + (size_t)bh * Nq;
    float mx = -INFINITY;
#pragma unroll
    for (int ii = 0; ii < 8; ii++) mx = fmaxf(mx, errow[threadIdx.x + ii * 256]);
#pragma unroll
    for (int off = 32; off > 0; off >>= 1) mx = fmaxf(mx, __shfl_xor(mx, off, 64));
    if (lane == 0) smax[kh] = mx;
    __syncthreads();
    const float emax = fmaxf(fmaxf(smax[0], smax[1]), fmaxf(smax[2], smax[3]));

    // ---- per-row broadcast (A,A) and (C,C) for 4 row-sets ----
    union HU { unsigned int u; half2v h; };
    HU AA2[4], CC2[4];
#pragma unroll
    for (int rs = 0; rs < 4; rs++) {
        float elv = el_t[(size_t)bh * Nq + i0 + rs * 16 + l15];
        float xm  = elv + emax;
        float m   = fmaxf(xm, NEG * xm);   // safe shift: s - m <= 0
        unsigned int a16 = f16u(__expf(elv - m));
        unsigned int c16 = f16u(__expf(NEG * elv - m));
        AA2[rs].u = a16 | (a16 << 16);
        CC2[rs].u = c16 | (c16 << 16);
    }

    const ushort* Ep = Epk + (size_t)bh * Nq + kh * 512;                    // + s*32
    const ushort* Fp = Fpk + (size_t)bh * Nq + kh * 512;                    // + s*32
    const ushort* vp = Vfrag + (size_t)bh * 131072 + kh * 32768 + lane * 8; // + s*2048
    const uint2*  mp = ebTB + ((size_t)(b * 256 + kh * 64 + quad)) * 2048 + i0 + l15;

    f32x4 zero4 = {0.f, 0.f, 0.f, 0.f};
    f32x4 acc[4][4];
    f32x4 accl[4];
#pragma unroll
    for (int rs = 0; rs < 4; rs++) {
        accl[rs] = zero4;
#pragma unroll
        for (int nf = 0; nf < 4; nf++) acc[rs][nf] = zero4;
    }

    const _Float16 one16 = (_Float16)1.0f;
    const half8 onesv = {one16, one16, one16, one16, one16, one16, one16, one16};

    for (int s = 0; s < 16; s++) {
        half8 vb0 = *(const half8*)(vp + s * 2048);
        half8 vb1 = *(const half8*)(vp + s * 2048 + 512);
        half8 vb2 = *(const half8*)(vp + s * 2048 + 1024);
        half8 vb3 = *(const half8*)(vp + s * 2048 + 1536);
        uint2 mbs[4];
#pragma unroll
        for (int rs = 0; rs < 4; rs++) mbs[rs] = mp[(size_t)s * 8192 + rs * 16];
        uint4 ev = *(const uint4*)(Ep + s * 32 + quad * 8);   // 4x (E_2p, E_2p+1)
        uint4 fv = *(const uint4*)(Fp + s * 32 + quad * 8);
        unsigned int ee[4] = {ev.x, ev.y, ev.z, ev.w};
        unsigned int ff[4] = {fv.x, fv.y, fv.z, fv.w};

#pragma unroll
        for (int rs = 0; rs < 4; rs++) {
            union AFU { half8 h8; unsigned int w4[4]; } af;
#pragma unroll
            for (int pp = 0; pp < 4; pp++) {
                HU e, f, pe, pf, P;
                e.u = ee[pp];
                f.u = ff[pp];
                pe.h = AA2[rs].h * e.h;                    // (A*E_2p, A*E_2p+1)
                pf.h = CC2[rs].h * f.h;                    // (C*F_2p, C*F_2p+1)
                P.h = __builtin_elementwise_max(pe.h, pf.h);
                unsigned int msrc = (pp < 2) ? mbs[rs].x : mbs[rs].y;
                unsigned int msel = (pp & 1) ? 0x03030202u : 0x01010000u;
                af.w4[pp] = P.u & __builtin_amdgcn_perm(0u, msrc, msel);
            }
            acc[rs][0] = __builtin_amdgcn_mfma_f32_16x16x32_f16(af.h8, vb0, acc[rs][0], 0, 0, 0);
            acc[rs][1] = __builtin_amdgcn_mfma_f32_16x16x32_f16(af.h8, vb1, acc[rs][1], 0, 0, 0);
            acc[rs][2] = __builtin_amdgcn_mfma_f32_16x16x32_f16(af.h8, vb2, acc[rs][2], 0, 0, 0);
            acc[rs][3] = __builtin_amdgcn_mfma_f32_16x16x32_f16(af.h8, vb3, acc[rs][3], 0, 0, 0);
            accl[rs]   = __builtin_amdgcn_mfma_f32_16x16x32_f16(af.h8, onesv, accl[rs], 0, 0, 0);
        }
    }

    // ---- cross-kh combine: store partials (acc + l), reduce rs=kh ----
#pragma unroll
    for (int rs = 0; rs < 4; rs++)
#pragma unroll
        for (int nf = 0; nf < 4; nf++)
            *(f32x4*)&lds_acc[kh][rs][nf][lane][0] = acc[rs][nf];
    if (l15 == 0) {
#pragma unroll
        for (int rs = 0; rs < 4; rs++)
#pragma unroll
            for (int r = 0; r < 4; r++)
                lds_l[kh][rs][quad * 4 + r] = accl[rs][r];
    }
    __syncthreads();

    const int rs = kh;
    f32x4 facc[4] = {zero4, zero4, zero4, zero4};
#pragma unroll
    for (int k2 = 0; k2 < 4; k2++)
#pragma unroll
        for (int nf = 0; nf < 4; nf++) {
            f32x4 v = *(const f32x4*)&lds_acc[k2][rs][nf][lane][0];
            facc[nf][0] += v[0]; facc[nf][1] += v[1];
            facc[nf][2] += v[2]; facc[nf][3] += v[3];
        }
    float rl[4];
#pragma unroll
    for (int r = 0; r < 4; r++) {
        float sl = 0.f;
#pragma unroll
        for (int k2 = 0; k2 < 4; k2++) sl += lds_l[k2][rs][quad * 4 + r];
        rl[r] = 1.0f / sl;
    }
#pragma unroll
    for (int nf = 0; nf < 4; nf++)
#pragma unroll
        for (int r = 0; r < 4; r++)
            attn[(((size_t)b * Nq + i0 + rs * 16 + quad * 4 + r) * Hq + h) * Fq + nf * 16 + l15]
                = (ushort)f16u(facc[nf][r] * rl[r]);
}

// ---------------------------------------------------------------------------
// Kernel 4: out[b,i,f] = sigmoid( mean_h attn[b,i,h,f] ), attn in fp16
// ---------------------------------------------------------------------------
__global__ __launch_bounds__(256) void out_kernel(
    const ushort* __restrict__ attn, float* __restrict__ out)
{
    const int idx = blockIdx.x * 256 + threadIdx.x;
    const int f   = idx & 63;
    const int bn  = idx >> 6;
    const ushort* p = attn + (size_t)bn * Hq * Fq + f;
    float s = 0.f;
#pragma unroll
    for (int h = 0; h < Hq; h++) {
        union { ushort u; _Float16 h16; } cv;
        cv.u = p[h * Fq];
        s += (float)cv.h16;
    }
    s *= (1.f / Hq);
    out[idx] = 1.f / (1.f + __expf(-s));
}

// ---------------------------------------------------------------------------
extern "C" void kernel_launch(void* const* d_in, const int* in_sizes, int n_in,
                              void* d_out, int out_size, void* d_ws, size_t ws_size,
                              hipStream_t stream) {
    const float* nodes = (const float*)d_in[0];   // (2,2048,512)
    const int*   edges = (const int*)d_in[1];     // (2,2048,2048,1)
    const float* W     = (const float*)d_in[2];   // (512,512)
    const float* a     = (const float*)d_in[3];   // (128,)
    float* out = (float*)d_out;                   // (2,2048,64)

    char* ws = (char*)d_ws;
    ushort* Afrag = (ushort*)ws;           ws += (size_t)Bq * Nq * DIN * 2;           // 4 MB
    ushort* Wfrag = (ushort*)ws;           ws += (size_t)DIN * Hq * Fq * 2;           // 512 KB
    ushort* Vfrag = (ushort*)ws;           ws += (size_t)Bq * Hq * Nq * Fq * 2;       // 4 MB
    float*  el_t  = (float*)ws;            ws += (size_t)Bq * Hq * Nq * 4;            // 128 KB
    float*  er_t  = (float*)ws;            ws += (size_t)Bq * Hq * Nq * 4;            // 128 KB
    ushort* Epk   = (ushort*)ws;           ws += (size_t)Bq * Hq * Nq * 2;            // 64 KB
    ushort* Fpk   = (ushort*)ws;           ws += (size_t)Bq * Hq * Nq * 2;            // 64 KB
    uint2*  ebTB  = (uint2*)ws;            ws += (size_t)Bq * Nq * Nq;                // 8.4 MB
    ushort* attn  = (ushort*)ws;                                                      // 4 MB

    prep_kernel<<<AFRAG_BLOCKS + WFRAG_BLOCKS, 256, 0, stream>>>(nodes, Afrag, W, Wfrag);
    work_kernel<<<GEMM_BLOCKS + PACK_BLOCKS, 256, 0, stream>>>(
        Afrag, Wfrag, a, Vfrag, el_t, er_t, Epk, Fpk, edges, ebTB);
    attn_kernel<<<Bq * Hq * (Nq / 64), 256, 0, stream>>>(el_t, er_t, Epk, Fpk, Vfrag, ebTB, attn);
    out_kernel<<<(Bq * Nq * Fq) / 256, 256, 0, stream>>>(attn, out);
}